// Round 6
// baseline (297.922 us; speedup 1.0000x reference)
//
#include <hip/hip_runtime.h>
#include <hip/hip_bf16.h>
#include <stdint.h>
#include <stddef.h>

typedef __bf16 bf16_t;
typedef __bf16 bf16x8 __attribute__((ext_vector_type(8)));
typedef float  f32x4  __attribute__((ext_vector_type(4)));

#define NN 1024
#define H  128
#define GRID 2048   // 256-thr blocks; each block: 8 tiles of 64 rows (16 rows/wave)

// ---------------- We fp32 -> bf16 ----------------
__global__ void k_cvt_we(const float* __restrict__ src, bf16_t* __restrict__ dst) {
    int i = blockIdx.x * 256 + threadIdx.x;
    if (i < H * H) dst[i] = (bf16_t)src[i];
}

// ---------------- f_i = node @ Wi^T, f_j = node @ Wj^T ----------------
__global__ void k_proj(const float* __restrict__ node,
                       const float* __restrict__ Wi,
                       const float* __restrict__ Wj,
                       bf16_t* __restrict__ fi,
                       bf16_t* __restrict__ fj) {
    __shared__ float nrow[H];
    const int row = blockIdx.x;
    const int t   = threadIdx.x;
    const int h   = t & (H - 1);
    const int sel = t >> 7;
    if (t < H) nrow[t] = node[(size_t)row * H + t];
    __syncthreads();
    const float* w = (sel ? Wj : Wi) + (size_t)h * H;
    float acc = 0.f;
    #pragma unroll
    for (int k4 = 0; k4 < H / 4; ++k4) {
        f32x4 wv = *(const f32x4*)(w + k4 * 4);
        f32x4 nv = *(const f32x4*)(&nrow[k4 * 4]);
        acc += nv[0] * wv[0] + nv[1] * wv[1] + nv[2] * wv[2] + nv[3] * wv[3];
    }
    bf16_t* dst = sel ? fj : fi;
    dst[(size_t)row * H + h] = (bf16_t)acc;
}

// ---------------- dots[i][j] = f_i[i] . f_j[j]  (grid 128: 16x8 tiles of 64x128) ----------------
__global__ __launch_bounds__(256, 4)
void k_dots(const bf16_t* __restrict__ fi,
            const bf16_t* __restrict__ fj,
            float* __restrict__ dots) {
    const int t    = threadIdx.x;
    const int wave = t >> 6;
    const int lane = t & 63;
    const int l15  = lane & 15;
    const int g    = lane >> 4;

    const int bm    = blockIdx.x >> 3;    // 0..15
    const int bn    = blockIdx.x & 7;     // 0..7
    const int ibase = bm * 64 + wave * 16;
    const int jbase = bn * 128;

    f32x4 acc[8];
    #pragma unroll
    for (int nt = 0; nt < 8; ++nt) acc[nt] = (f32x4){0.f, 0.f, 0.f, 0.f};

    const bf16_t* a = fi + (size_t)(ibase + l15) * H + g * 8;

    #pragma unroll
    for (int kst = 0; kst < 4; ++kst) {
        bf16x8 af = *(const bf16x8*)(a + kst * 32);
        #pragma unroll
        for (int nt = 0; nt < 8; ++nt) {
            bf16x8 bf = *(const bf16x8*)(fj + (size_t)(jbase + nt * 16 + l15) * H + kst * 32 + g * 8);
            acc[nt] = __builtin_amdgcn_mfma_f32_16x16x32_bf16(af, bf, acc[nt], 0, 0, 0);
        }
    }

    const int rbase = ibase + g * 4;
    #pragma unroll
    for (int r = 0; r < 4; ++r)
        #pragma unroll
        for (int nt = 0; nt < 8; ++nt)
            dots[(size_t)(rbase + r) * NN + jbase + nt * 16 + l15] = acc[nt][r];
}

// ---------------- async global -> LDS (16B/lane, dest = uniform base + lane*16) ----------------
__device__ __forceinline__ void gl_lds16(const float* g, float* l) {
    __builtin_amdgcn_global_load_lds(
        (const __attribute__((address_space(1))) unsigned int*)g,
        (__attribute__((address_space(3))) unsigned int*)l,
        16, 0, 0);
}

// ---------------- main: out = relu(edge @ We^T + be + dots[row]) ----------------
// R5 pipeline + LDS-transpose epilogue: stores now cover 2 full 512B rows per
// dwordx4 instruction (was 16 x 64B segments at 512B stride), matching the
// load path's geometry. Transpose reuses the just-consumed staging buffer
// (wave-private rows, no barriers). Staging moved to end-of-iteration;
// counted vmcnt re-derived: 8 at k in {0,7}, 16 otherwise (depth ~1.3 iter).
__global__ __launch_bounds__(256, 2)
void k_main(const float* __restrict__ edge,   // [1M][128] fp32
            const bf16_t* __restrict__ web,   // [128][128] bf16
            const float* __restrict__ be,     // [128]
            const float* __restrict__ dots,   // [1M]
            float* __restrict__ out) {        // [1M][128] fp32
    __shared__ __align__(16) float bufA[64][H];   // 32 KB
    __shared__ __align__(16) float bufB[64][H];   // 32 KB
    __shared__ float lbias[H];

    const int t     = threadIdx.x;
    const int wave  = t >> 6;
    const int lane  = t & 63;
    const int l15   = lane & 15;
    const int g     = lane >> 4;
    const int lhalf = lane >> 5;            // staging: which row of the pair
    const int b16   = (lane & 31) * 16;     // staging: byte within 512B row

    if (t < H) lbias[t] = be[t];
    __syncthreads();

    // ---- prologue: pinned register state (web fragments + dots) ----
    bf16x8 wfr[8][4];
    {
        const bf16_t* wp = web + (size_t)l15 * H + g * 8;
        #pragma unroll
        for (int nt = 0; nt < 8; ++nt)
            #pragma unroll
            for (int kk = 0; kk < 4; ++kk)
                wfr[nt][kk] = *(const bf16x8*)(wp + (size_t)(nt * 16) * H + kk * 32);
    }
    float dvv[8];
    #pragma unroll
    for (int k = 0; k < 8; ++k)
        dvv[k] = dots[(size_t)(blockIdx.x + k * GRID) * 64 + wave * 16 + l15];

    #pragma unroll
    for (int nt = 0; nt < 8; ++nt) {
        #pragma unroll
        for (int kk = 0; kk < 4; ++kk)
            asm volatile("" : "+v"(wfr[nt][kk]));
        asm volatile("" : "+v"(dvv[nt]));
    }

    // ---- staging: LDS linear dest, global source pre-swizzled (involution) ----
    #define STAGE(K, BUFP)                                                       \
        {                                                                        \
            const char* tb = (const char*)(edge + ((size_t)(blockIdx.x + (K) * GRID) * 64 + wave * 16) * H); \
            _Pragma("unroll")                                                    \
            for (int i = 0; i < 8; ++i) {                                        \
                const int r = 2 * i + lhalf;                                     \
                const int srcoff = r * 512 + (b16 ^ ((r & 7) << 4));             \
                gl_lds16((const float*)(tb + srcoff), &BUFP[wave * 16 + 2 * i][0]); \
            }                                                                    \
        }

    STAGE(0, bufA)
    STAGE(1, bufB)

    const int sw = (l15 & 7) << 4;   // fragment-read swizzle (same involution)

    #pragma unroll
    for (int k = 0; k < 8; ++k) {
        // queue at top (oldest->youngest), steady: stage(k), stores(k-1), stage(k+1)
        // -> need stage(k) drained: keep 16. k==0: only stage0,stage1 -> keep 8.
        // k==7: stage7, stores6 -> keep 8.
        if (k == 0 || k == 7) asm volatile("s_waitcnt vmcnt(8)"  ::: "memory");
        else                  asm volatile("s_waitcnt vmcnt(16)" ::: "memory");
        __builtin_amdgcn_sched_barrier(0);

        char* curb = (char*)((k & 1) ? &bufB[0][0] : &bufA[0][0]);

        // 1) fragment reads (tile k) to regs
        const char* lrow = curb + (wave * 16 + l15) * 512;
        f32x4 u[8];
        #pragma unroll
        for (int kk = 0; kk < 4; ++kk) {
            u[2 * kk]     = *(const f32x4*)(lrow + kk * 128 + ((g * 32 +  0) ^ sw));
            u[2 * kk + 1] = *(const f32x4*)(lrow + kk * 128 + ((g * 32 + 16) ^ sw));
        }

        // 2) acc init = bias (LDS broadcast) + dot, then MFMA from regs
        const float dv = dvv[k];
        f32x4 acc[8];
        #pragma unroll
        for (int nt = 0; nt < 8; ++nt) {
            f32x4 bv = *(const f32x4*)(&lbias[nt * 16 + g * 4]);
            #pragma unroll
            for (int r = 0; r < 4; ++r) acc[nt][r] = bv[r] + dv;
        }

        #pragma unroll
        for (int kk = 0; kk < 4; ++kk) {
            bf16x8 bfrag;
            #pragma unroll
            for (int i2 = 0; i2 < 4; ++i2) {
                bfrag[i2]     = (bf16_t)u[2 * kk][i2];
                bfrag[i2 + 4] = (bf16_t)u[2 * kk + 1][i2];
            }
            #pragma unroll
            for (int nt = 0; nt < 8; ++nt)
                acc[nt] = __builtin_amdgcn_mfma_f32_16x16x32_bf16(wfr[nt][kk], bfrag, acc[nt], 0, 0, 0);
        }

        // 3) relu + transpose-write into the just-consumed buffer (wave-private)
        //    lane (g,l15) holds logical row l15 bytes [nt*64+g*16, +16)
        #pragma unroll
        for (int nt = 0; nt < 8; ++nt) {
            f32x4 v;
            #pragma unroll
            for (int r = 0; r < 4; ++r) v[r] = fmaxf(acc[nt][r], 0.f);
            *(f32x4*)(curb + (wave * 16 + l15) * 512 + ((nt * 64 + g * 16) ^ sw)) = v;
        }

        // 4) read back lane-contiguous, store 2 full rows (1KB) per instruction
        const size_t rowbase = (size_t)(blockIdx.x + k * GRID) * 64 + wave * 16;
        #pragma unroll
        for (int j = 0; j < 8; ++j) {
            const int row = 2 * j + lhalf;          // 0..15 within wave slice
            const int c16 = (lane & 31) * 16;       // byte chunk within row
            f32x4 v = *(const f32x4*)(curb + (wave * 16 + row) * 512
                                           + (c16 ^ ((row & 7) << 4)));
            *(f32x4*)((char*)(out + (rowbase + row) * H) + c16) = v;
        }

        // 5) stage tile k+2 into this buffer (after read-back in program order)
        __builtin_amdgcn_sched_barrier(0);
        if (k < 6) {
            if (k & 1) { STAGE(k + 2, bufB) }
            else       { STAGE(k + 2, bufA) }
        }
    }
    #undef STAGE
}

extern "C" void kernel_launch(void* const* d_in, const int* in_sizes, int n_in,
                              void* d_out, int out_size, void* d_ws, size_t ws_size,
                              hipStream_t stream) {
    const float* node = (const float*)d_in[0];
    const float* edge = (const float*)d_in[1];
    const float* We   = (const float*)d_in[2];
    const float* be   = (const float*)d_in[3];
    const float* Wi   = (const float*)d_in[4];
    const float* Wj   = (const float*)d_in[5];
    float* out = (float*)d_out;

    char* w = (char*)d_ws;
    bf16_t* fi_bf = (bf16_t*)w;                              // 256 KB
    bf16_t* fj_bf = (bf16_t*)(w + (256 << 10));              // 256 KB
    float*  dots  = (float*)(w + (512 << 10));               // 4 MB
    bf16_t* web   = (bf16_t*)(w + (512 << 10) + (4 << 20));  // 32 KB

    k_cvt_we<<<(H * H + 255) / 256, 256, 0, stream>>>(We, web);
    k_proj<<<NN, 256, 0, stream>>>(node, Wi, Wj, fi_bf, fj_bf);
    k_dots<<<128, 256, 0, stream>>>(fi_bf, fj_bf, dots);
    k_main<<<GRID, 256, 0, stream>>>(edge, web, be, dots, out);
}

// Round 7
// 242.768 us; speedup vs baseline: 1.2272x; 1.2272x over previous
//
#include <hip/hip_runtime.h>
#include <hip/hip_bf16.h>
#include <stdint.h>
#include <stddef.h>

typedef __bf16 bf16_t;
typedef __bf16 bf16x8 __attribute__((ext_vector_type(8)));
typedef float  f32x4  __attribute__((ext_vector_type(4)));
typedef float  f32x16 __attribute__((ext_vector_type(16)));

#define NN 1024
#define H  128
#define GRID 2048   // 128-thr (2-wave) blocks; 8 consecutive 64-row tiles per block

// ---------------- We fp32 -> bf16 ----------------
__global__ void k_cvt_we(const float* __restrict__ src, bf16_t* __restrict__ dst) {
    int i = blockIdx.x * 256 + threadIdx.x;
    if (i < H * H) dst[i] = (bf16_t)src[i];
}

// ---------------- f_i = node @ Wi^T, f_j = node @ Wj^T ----------------
__global__ void k_proj(const float* __restrict__ node,
                       const float* __restrict__ Wi,
                       const float* __restrict__ Wj,
                       bf16_t* __restrict__ fi,
                       bf16_t* __restrict__ fj) {
    __shared__ float nrow[H];
    const int row = blockIdx.x;
    const int t   = threadIdx.x;
    const int h   = t & (H - 1);
    const int sel = t >> 7;
    if (t < H) nrow[t] = node[(size_t)row * H + t];
    __syncthreads();
    const float* w = (sel ? Wj : Wi) + (size_t)h * H;
    float acc = 0.f;
    #pragma unroll
    for (int k4 = 0; k4 < H / 4; ++k4) {
        f32x4 wv = *(const f32x4*)(w + k4 * 4);
        f32x4 nv = *(const f32x4*)(&nrow[k4 * 4]);
        acc += nv[0] * wv[0] + nv[1] * wv[1] + nv[2] * wv[2] + nv[3] * wv[3];
    }
    bf16_t* dst = sel ? fj : fi;
    dst[(size_t)row * H + h] = (bf16_t)acc;
}

// ---------------- dots[i][j] = f_i[i] . f_j[j]  (grid 128: 16x8 tiles of 64x128) ----------------
__global__ __launch_bounds__(256, 4)
void k_dots(const bf16_t* __restrict__ fi,
            const bf16_t* __restrict__ fj,
            float* __restrict__ dots) {
    const int t    = threadIdx.x;
    const int wave = t >> 6;
    const int lane = t & 63;
    const int l15  = lane & 15;
    const int g    = lane >> 4;

    const int bm    = blockIdx.x >> 3;    // 0..15
    const int bn    = blockIdx.x & 7;     // 0..7
    const int ibase = bm * 64 + wave * 16;
    const int jbase = bn * 128;

    f32x4 acc[8];
    #pragma unroll
    for (int nt = 0; nt < 8; ++nt) acc[nt] = (f32x4){0.f, 0.f, 0.f, 0.f};

    const bf16_t* a = fi + (size_t)(ibase + l15) * H + g * 8;

    #pragma unroll
    for (int kst = 0; kst < 4; ++kst) {
        bf16x8 af = *(const bf16x8*)(a + kst * 32);
        #pragma unroll
        for (int nt = 0; nt < 8; ++nt) {
            bf16x8 bf = *(const bf16x8*)(fj + (size_t)(jbase + nt * 16 + l15) * H + kst * 32 + g * 8);
            acc[nt] = __builtin_amdgcn_mfma_f32_16x16x32_bf16(af, bf, acc[nt], 0, 0, 0);
        }
    }

    const int rbase = ibase + g * 4;
    #pragma unroll
    for (int r = 0; r < 4; ++r)
        #pragma unroll
        for (int nt = 0; nt < 8; ++nt)
            dots[(size_t)(rbase + r) * NN + jbase + nt * 16 + l15] = acc[nt][r];
}

// ---------------- async global -> LDS (16B/lane, dest = uniform base + lane*16) ----------------
__device__ __forceinline__ void gl_lds16(const float* g, float* l) {
    __builtin_amdgcn_global_load_lds(
        (const __attribute__((address_space(1))) unsigned int*)g,
        (__attribute__((address_space(3))) unsigned int*)l,
        16, 0, 0);
}

// ---------------- main: out = relu(edge @ We^T + be + dots[row]) ----------------
// 32x32x16 MFMA variant: D layout col=lane&31 (out col), row from regs (edge
// row) -> each (nt,reg) scalar store covers two FULL 128B lines (32 lanes x 4B
// per half-wave). Kills the 64B-chunk write amplification of the 16x16 path
// without any LDS/shuffle epilogue. 2-wave blocks, 32 rows/wave/tile, 8
// consecutive tiles/block; wave-private staging + counted vmcnt (in-loop vmem
// = 16 gl_lds + 64 stores -> vmcnt(48) drains stage(k)+16 ancient stores).
// dots staged once in prologue (wave-redundant) so the loop queue stays exact.
__global__ __launch_bounds__(128, 1)
void k_main(const float* __restrict__ edge,   // [1M][128] fp32
            const bf16_t* __restrict__ web,   // [128][128] bf16
            const float* __restrict__ be,     // [128]
            const float* __restrict__ dots,   // [1M]
            float* __restrict__ out) {        // [1M][128] fp32
    __shared__ __align__(16) float ebuf[2][2][32][H];  // [buf][wave][row][col] 64 KB
    __shared__ __align__(16) float dbuf[2][512];       // [wave][row] dots, 4 KB

    const int t    = threadIdx.x;       // 0..127
    const int wave = t >> 6;
    const int lane = t & 63;
    const int l31  = lane & 31;
    const int h    = lane >> 5;
    const size_t base = (size_t)blockIdx.x * 512;      // first edge row of block

    // ---- prologue: We fragments + bias in regs (pinned), dots -> LDS ----
    // wfr[nt][kk]: B operand, col j = nt*32+l31 (We row), k = kk*16 + h*8 + e
    bf16x8 wfr[4][8];
    {
        const bf16_t* wp = web + (size_t)l31 * H + h * 8;
        #pragma unroll
        for (int nt = 0; nt < 4; ++nt)
            #pragma unroll
            for (int kk = 0; kk < 8; ++kk)
                wfr[nt][kk] = *(const bf16x8*)(wp + (size_t)(nt * 32) * H + kk * 16);
    }
    float bias[4];
    #pragma unroll
    for (int nt = 0; nt < 4; ++nt) bias[nt] = be[nt * 32 + l31];

    #pragma unroll
    for (int nt = 0; nt < 4; ++nt) {
        #pragma unroll
        for (int kk = 0; kk < 8; ++kk)
            asm volatile("" : "+v"(wfr[nt][kk]));
        asm volatile("" : "+v"(bias[nt]));
    }
    // Pins force the prologue loads to drain here -> loop vmem queue is exact.

    // dots for the block's 512 rows, staged wave-redundantly (no cross-wave dep)
    gl_lds16(dots + base + lane * 4,       &dbuf[wave][0]);
    gl_lds16(dots + base + 256 + lane * 4, &dbuf[wave][256]);

    // ---- edge staging: LDS linear dest, global source pre-swizzled ----
    #define STAGE(K, BI)                                                         \
        {                                                                        \
            const char* tb = (const char*)(edge + (base + (size_t)(K) * 64 + wave * 32) * H); \
            _Pragma("unroll")                                                    \
            for (int i = 0; i < 16; ++i) {                                       \
                const int rr = 2 * i + h;                                        \
                gl_lds16((const float*)(tb + rr * 512 + ((l31 * 16) ^ ((rr & 7) << 4))), \
                         &ebuf[BI][wave][2 * i][0]);                             \
            }                                                                    \
        }

    STAGE(0, 0)

    const int sw = (l31 & 7) << 4;   // read-side swizzle (same involution)

    #pragma unroll
    for (int k = 0; k < 8; ++k) {
        // top of iter k queue (old->young): stage(k)[16], stores(k-1)[64].
        // keep 48 -> drains stage(k) + 16 epoch-old stores. k=0: drain all
        // (also covers the prologue dots staging before first dbuf read).
        if (k == 0) asm volatile("s_waitcnt vmcnt(0)"  ::: "memory");
        else        asm volatile("s_waitcnt vmcnt(48)" ::: "memory");
        __builtin_amdgcn_sched_barrier(0);

        // 1) fragment reads for tile k (before any new gl_lds in program order)
        const char* erow = (const char*)&ebuf[k & 1][wave][0][0] + l31 * 512;
        f32x4 ua[8], ub[8];
        #pragma unroll
        for (int kk = 0; kk < 8; ++kk) {
            ua[kk] = *(const f32x4*)(erow + ((kk * 64 + h * 32 +  0) ^ sw));
            ub[kk] = *(const f32x4*)(erow + ((kk * 64 + h * 32 + 16) ^ sw));
        }

        // 2) stage tile k+1 into the other buffer (in flight across MFMA)
        if (k < 7) {
            if (k & 1) { STAGE(k + 1, 0) }
            else       { STAGE(k + 1, 1) }
        }

        // 3) acc init = bias(col, lane-based) + dots(row, reg-based)
        const float* dl = &dbuf[wave][k * 64 + wave * 32];
        f32x4 dv[4];
        #pragma unroll
        for (int b = 0; b < 4; ++b)
            dv[b] = *(const f32x4*)(dl + 4 * h + 8 * b);

        f32x16 acc[4];
        #pragma unroll
        for (int nt = 0; nt < 4; ++nt)
            #pragma unroll
            for (int r = 0; r < 16; ++r)
                acc[nt][r] = bias[nt] + dv[r >> 2][r & 3];

        // 4) MFMA: A = edge rows (lane&31=row, k=h*8+e), B = We (lane&31=col)
        #pragma unroll
        for (int kk = 0; kk < 8; ++kk) {
            bf16x8 af;
            #pragma unroll
            for (int e = 0; e < 4; ++e) {
                af[e]     = (bf16_t)ua[kk][e];
                af[e + 4] = (bf16_t)ub[kk][e];
            }
            #pragma unroll
            for (int nt = 0; nt < 4; ++nt)
                acc[nt] = __builtin_amdgcn_mfma_f32_32x32x16_bf16(af, wfr[nt][kk], acc[nt], 0, 0, 0);
        }

        // 5) full-line stores: per (nt,r) 32 lanes x 4B = one 128B line per
        //    half-wave (rows 4h + (r&3) + 8*(r>>2), cols nt*32 + l31)
        float* orow = out + (base + (size_t)k * 64 + wave * 32 + 4 * h) * H + l31;
        #pragma unroll
        for (int nt = 0; nt < 4; ++nt)
            #pragma unroll
            for (int r = 0; r < 16; ++r)
                orow[((r & 3) + 8 * (r >> 2)) * H + nt * 32] = fmaxf(acc[nt][r], 0.f);
    }
    #undef STAGE
}

extern "C" void kernel_launch(void* const* d_in, const int* in_sizes, int n_in,
                              void* d_out, int out_size, void* d_ws, size_t ws_size,
                              hipStream_t stream) {
    const float* node = (const float*)d_in[0];
    const float* edge = (const float*)d_in[1];
    const float* We   = (const float*)d_in[2];
    const float* be   = (const float*)d_in[3];
    const float* Wi   = (const float*)d_in[4];
    const float* Wj   = (const float*)d_in[5];
    float* out = (float*)d_out;

    char* w = (char*)d_ws;
    bf16_t* fi_bf = (bf16_t*)w;                              // 256 KB
    bf16_t* fj_bf = (bf16_t*)(w + (256 << 10));              // 256 KB
    float*  dots  = (float*)(w + (512 << 10));               // 4 MB
    bf16_t* web   = (bf16_t*)(w + (512 << 10) + (4 << 20));  // 32 KB

    k_cvt_we<<<(H * H + 255) / 256, 256, 0, stream>>>(We, web);
    k_proj<<<NN, 256, 0, stream>>>(node, Wi, Wj, fi_bf, fj_bf);
    k_dots<<<128, 256, 0, stream>>>(fi_bf, fj_bf, dots);
    k_main<<<GRID, 128, 0, stream>>>(edge, web, be, dots, out);
}

// Round 8
// 237.289 us; speedup vs baseline: 1.2555x; 1.0231x over previous
//
#include <hip/hip_runtime.h>
#include <hip/hip_bf16.h>
#include <stdint.h>
#include <stddef.h>

typedef __bf16 bf16_t;
typedef __bf16 bf16x8 __attribute__((ext_vector_type(8)));
typedef float  f32x4  __attribute__((ext_vector_type(4)));
typedef float  f32x16 __attribute__((ext_vector_type(16)));

#define NN 1024
#define H  128
#define GRID 2048   // 256-thr blocks; 8 consecutive 64-row tiles per block

// ---------------- We fp32 -> bf16 ----------------
__global__ void k_cvt_we(const float* __restrict__ src, bf16_t* __restrict__ dst) {
    int i = blockIdx.x * 256 + threadIdx.x;
    if (i < H * H) dst[i] = (bf16_t)src[i];
}

// ---------------- f_i = node @ Wi^T, f_j = node @ Wj^T ----------------
__global__ void k_proj(const float* __restrict__ node,
                       const float* __restrict__ Wi,
                       const float* __restrict__ Wj,
                       bf16_t* __restrict__ fi,
                       bf16_t* __restrict__ fj) {
    __shared__ float nrow[H];
    const int row = blockIdx.x;
    const int t   = threadIdx.x;
    const int h   = t & (H - 1);
    const int sel = t >> 7;
    if (t < H) nrow[t] = node[(size_t)row * H + t];
    __syncthreads();
    const float* w = (sel ? Wj : Wi) + (size_t)h * H;
    float acc = 0.f;
    #pragma unroll
    for (int k4 = 0; k4 < H / 4; ++k4) {
        f32x4 wv = *(const f32x4*)(w + k4 * 4);
        f32x4 nv = *(const f32x4*)(&nrow[k4 * 4]);
        acc += nv[0] * wv[0] + nv[1] * wv[1] + nv[2] * wv[2] + nv[3] * wv[3];
    }
    bf16_t* dst = sel ? fj : fi;
    dst[(size_t)row * H + h] = (bf16_t)acc;
}

// ---------------- dots[i][j] = f_i[i] . f_j[j]  (grid 128: 16x8 tiles of 64x128) ----------------
__global__ __launch_bounds__(256, 4)
void k_dots(const bf16_t* __restrict__ fi,
            const bf16_t* __restrict__ fj,
            float* __restrict__ dots) {
    const int t    = threadIdx.x;
    const int wave = t >> 6;
    const int lane = t & 63;
    const int l15  = lane & 15;
    const int g    = lane >> 4;

    const int bm    = blockIdx.x >> 3;
    const int bn    = blockIdx.x & 7;
    const int ibase = bm * 64 + wave * 16;
    const int jbase = bn * 128;

    f32x4 acc[8];
    #pragma unroll
    for (int nt = 0; nt < 8; ++nt) acc[nt] = (f32x4){0.f, 0.f, 0.f, 0.f};

    const bf16_t* a = fi + (size_t)(ibase + l15) * H + g * 8;

    #pragma unroll
    for (int kst = 0; kst < 4; ++kst) {
        bf16x8 af = *(const bf16x8*)(a + kst * 32);
        #pragma unroll
        for (int nt = 0; nt < 8; ++nt) {
            bf16x8 bf = *(const bf16x8*)(fj + (size_t)(jbase + nt * 16 + l15) * H + kst * 32 + g * 8);
            acc[nt] = __builtin_amdgcn_mfma_f32_16x16x32_bf16(af, bf, acc[nt], 0, 0, 0);
        }
    }

    const int rbase = ibase + g * 4;
    #pragma unroll
    for (int r = 0; r < 4; ++r)
        #pragma unroll
        for (int nt = 0; nt < 8; ++nt)
            dots[(size_t)(rbase + r) * NN + jbase + nt * 16 + l15] = acc[nt][r];
}

// ---------------- async global -> LDS (16B/lane, dest = uniform base + lane*16) ----------------
__device__ __forceinline__ void gl_lds16(const float* g, float* l) {
    __builtin_amdgcn_global_load_lds(
        (const __attribute__((address_space(1))) unsigned int*)g,
        (__attribute__((address_space(3))) unsigned int*)l,
        16, 0, 0);
}

// ---------------- main: out = relu(edge @ We^T + be + dots[row]) ----------------
// CONTROL variant: simplest correct double-buffer. No inline-asm waits, no
// sched_barrier fences, no register pins -- one __syncthreads per tile,
// compiler-scheduled waitcnts. 4 waves split each 64x128 tile 2x2 (wave
// (wm,wn): rows wm*32+[0,32), cols wn*64+[0,64)). 32x32x16 MFMA layout
// (validated R7): full 128B-line stores. LDS 2x32KB dbuf -> 2 blocks/CU,
// so barrier drains in one block overlap streaming in the other.
__global__ __launch_bounds__(256)
void k_main(const float* __restrict__ edge,   // [1M][128] fp32
            const bf16_t* __restrict__ web,   // [128][128] bf16
            const float* __restrict__ be,     // [128]
            const float* __restrict__ dots,   // [1M]
            float* __restrict__ out) {        // [1M][128] fp32
    __shared__ __align__(16) float bufA[64][H];   // 32 KB
    __shared__ __align__(16) float bufB[64][H];   // 32 KB
    __shared__ float ldots[512];

    const int t    = threadIdx.x;       // 0..255
    const int w    = t >> 6;            // wave 0..3
    const int lane = t & 63;
    const int l31  = lane & 31;
    const int h    = lane >> 5;
    const int wm   = w & 1;             // row half
    const int wn   = w >> 1;            // col half
    const size_t base = (size_t)blockIdx.x * 512;   // first edge row of block

    // dots for the block's 512 rows -> LDS
    ldots[t]       = dots[base + t];
    ldots[256 + t] = dots[base + 256 + t];

    // We fragments: B operand, col = wn*64 + nt*32 + l31, k = kk*16 + h*8 + e
    bf16x8 wfr[2][8];
    {
        const bf16_t* wp = web + (size_t)(wn * 64 + l31) * H + h * 8;
        #pragma unroll
        for (int nt = 0; nt < 2; ++nt)
            #pragma unroll
            for (int kk = 0; kk < 8; ++kk)
                wfr[nt][kk] = *(const bf16x8*)(wp + (size_t)(nt * 32) * H + kk * 16);
    }
    float bias[2];
    #pragma unroll
    for (int nt = 0; nt < 2; ++nt) bias[nt] = be[wn * 64 + nt * 32 + l31];

    // staging: wave w covers rows [w*16, w*16+16) of the 64-row tile;
    // LDS dest linear, global source pre-swizzled (XOR involution per row).
    #define STAGE(K, BUFP)                                                       \
        {                                                                        \
            const char* tb = (const char*)(edge + (base + (size_t)(K) * 64) * H); \
            _Pragma("unroll")                                                    \
            for (int i = 0; i < 8; ++i) {                                        \
                const int rr = w * 16 + 2 * i + h;                               \
                gl_lds16((const float*)(tb + rr * 512 + ((l31 * 16) ^ ((rr & 7) << 4))), \
                         &BUFP[w * 16 + 2 * i][0]);                              \
            }                                                                    \
        }

    STAGE(0, bufA)

    const int sw = (l31 & 7) << 4;   // read-side swizzle (same involution)

    #pragma unroll 1
    for (int k = 0; k < 8; ++k) {
        __syncthreads();   // tile k staged (compiler inserts the vmcnt wait)

        const char* crow = (const char*)((k & 1) ? &bufB[0][0] : &bufA[0][0])
                         + (wm * 32 + l31) * 512;

        // fragment reads for tile k: A rows = wm*32 + l31, k = kk*16 + h*8 + e
        f32x4 ua[8], ub[8];
        #pragma unroll
        for (int kk = 0; kk < 8; ++kk) {
            ua[kk] = *(const f32x4*)(crow + ((kk * 64 + h * 32 +  0) ^ sw));
            ub[kk] = *(const f32x4*)(crow + ((kk * 64 + h * 32 + 16) ^ sw));
        }

        // stage tile k+1 into the other buffer (its previous readers finished
        // before the barrier above)
        if (k < 7) {
            if (k & 1) { STAGE(k + 1, bufA) }
            else       { STAGE(k + 1, bufB) }
        }

        // acc init = bias(col) + dots(row); row r = wm*32 + 4h + (reg&3) + 8*(reg>>2)
        f32x4 dv[4];
        #pragma unroll
        for (int b = 0; b < 4; ++b)
            dv[b] = *(const f32x4*)(&ldots[k * 64 + wm * 32 + 4 * h + 8 * b]);

        f32x16 acc[2];
        #pragma unroll
        for (int nt = 0; nt < 2; ++nt)
            #pragma unroll
            for (int r = 0; r < 16; ++r)
                acc[nt][r] = bias[nt] + dv[r >> 2][r & 3];

        #pragma unroll
        for (int kk = 0; kk < 8; ++kk) {
            bf16x8 af;
            #pragma unroll
            for (int e = 0; e < 4; ++e) {
                af[e]     = (bf16_t)ua[kk][e];
                af[e + 4] = (bf16_t)ub[kk][e];
            }
            #pragma unroll
            for (int nt = 0; nt < 2; ++nt)
                acc[nt] = __builtin_amdgcn_mfma_f32_32x32x16_bf16(af, wfr[nt][kk], acc[nt], 0, 0, 0);
        }

        // full-line stores: per (nt,reg) each half-wave writes one 128B line
        float* orow = out + (base + (size_t)k * 64 + wm * 32 + 4 * h) * H + wn * 64 + l31;
        #pragma unroll
        for (int nt = 0; nt < 2; ++nt)
            #pragma unroll
            for (int r = 0; r < 16; ++r)
                orow[((r & 3) + 8 * (r >> 2)) * H + nt * 32] = fmaxf(acc[nt][r], 0.f);
    }
    #undef STAGE
}

extern "C" void kernel_launch(void* const* d_in, const int* in_sizes, int n_in,
                              void* d_out, int out_size, void* d_ws, size_t ws_size,
                              hipStream_t stream) {
    const float* node = (const float*)d_in[0];
    const float* edge = (const float*)d_in[1];
    const float* We   = (const float*)d_in[2];
    const float* be   = (const float*)d_in[3];
    const float* Wi   = (const float*)d_in[4];
    const float* Wj   = (const float*)d_in[5];
    float* out = (float*)d_out;

    char* w = (char*)d_ws;
    bf16_t* fi_bf = (bf16_t*)w;                              // 256 KB
    bf16_t* fj_bf = (bf16_t*)(w + (256 << 10));              // 256 KB
    float*  dots  = (float*)(w + (512 << 10));               // 4 MB
    bf16_t* web   = (bf16_t*)(w + (512 << 10) + (4 << 20));  // 32 KB

    k_cvt_we<<<(H * H + 255) / 256, 256, 0, stream>>>(We, web);
    k_proj<<<NN, 256, 0, stream>>>(node, Wi, Wj, fi_bf, fj_bf);
    k_dots<<<128, 256, 0, stream>>>(fi_bf, fj_bf, dots);
    k_main<<<GRID, 256, 0, stream>>>(edge, web, be, dots, out);
}